// Round 11
// baseline (88.891 us; speedup 1.0000x reference)
//
#include <hip/hip_runtime.h>

// PhysicsInformedLoss on (16,3,1024,512) f32 y_hat + (16,2,1024,512) i32 x_in.
// R11: persistent double-buffered global_load_lds pipeline (T3/T4 pattern).
// 256 blocks (1/CU) x 512 thr; each block marches 8 tiles of TR=8 rows.
// Dynamic LDS 120KB = 2 x (3 fields x 10 rows x 512). Counted vmcnt (never 0
// mid-loop) + raw s_barrier keeps the DMA queue full across tiles.
// R5/R6 lesson: no device fences; two-kernel reduce.

namespace {
constexpr int NXc  = 1024;
constexpr int NYc  = 512;
constexpr int NXYc = NXc * NYc;
constexpr int NBc  = 16;
constexpr int NTHR = 512;               // 8 waves
constexpr int NACC = 10;
constexpr int TR   = 8;                 // rows per tile
constexpr int TPB  = 8;                 // tiles per block -> 64 rows/block
constexpr int NBLK = NBc * NXc / (TR * TPB);   // 256 blocks (16 per batch)
constexpr int NXCD = 8;
constexpr int QX   = NBLK / NXCD;       // 32 (exact -> bijective swizzle)
constexpr int BUFE = 3 * (TR + 2) * NYc;       // 15360 floats per buffer
// acc: 0 s_div2, 1 s_resx2, 2 s_resy2, 3 n_interior,
//      4 s_noslip, 5 n_noslip, 6 s_inlet, 7 n_inlet, 8 s_outlet, 9 n_outlet
}

__global__ __launch_bounds__(NTHR) void pil_main(const float* __restrict__ y,
                                                 const int* __restrict__ xin,
                                                 float* __restrict__ partial) {
  extern __shared__ float lds[];        // [2][3][10][512] = 120 KB

  constexpr double DXd = 0.26 / 1023.0;
  constexpr double DYd = 0.12 / 511.0;
  const float INV2DX = (float)(1.0 / (2.0 * DXd));
  const float INV2DY = (float)(1.0 / (2.0 * DYd));
  const float INVDX2 = (float)(1.0 / (DXd * DXd));
  const float INVDY2 = (float)(1.0 / (DYd * DYd));
  constexpr float NU = 1e-4f;
  constexpr float U_INLET = 0.1f;

  const int l   = threadIdx.x & 63;
  const int w   = threadIdx.x >> 6;     // wave 0..7
  const int swz = (blockIdx.x % NXCD) * QX + blockIdx.x / NXCD;  // bijective
  const int b   = swz >> 4;             // 16 blocks per batch
  const int sub = swz & 15;
  const int bi0 = sub * (TR * TPB);     // block's first row (64-row span)

  const float* __restrict__ ux = y + (size_t)b * 3 * NXYc;
  const float* __restrict__ uy = ux + NXYc;
  const float* __restrict__ pp = ux + 2 * NXYc;
  const int*   __restrict__ rp = xin + (size_t)(2 * b + 1) * NXYc;

  // stage tile t (first compute row bi0+t*TR) into buffer q.
  // 60 chunks of 1KB: f = c/20, rw = (c%20)>>1, h = c&1.
  // waves 0-3 issue 8 chunks, waves 4-7 issue 7.
  auto stage = [&](int t, int q) {
    const int ti0 = bi0 + t * TR;
#pragma unroll
    for (int k = 0; k < 8; ++k) {
      const int c = k * 8 + w;
      if (c < 60) {
        const int f  = c / 20;
        const int cc = c % 20;
        const int rw = cc >> 1;
        const int h  = cc & 1;
        int gi = ti0 - 1 + rw;
        gi = gi < 0 ? 0 : (gi > NXc - 1 ? NXc - 1 : gi);   // edge clamp
        const float* base = (f == 0) ? ux : ((f == 1) ? uy : pp);
        const float* g = base + gi * NYc + h * 256 + l * 4;
        float* d = lds + q * BUFE + f * ((TR + 2) * NYc) + rw * NYc + h * 256;
        __builtin_amdgcn_global_load_lds(
            (const __attribute__((address_space(1))) void*)g,
            (__attribute__((address_space(3))) void*)d, 16, 0, 0);
      }
    }
  };

  float a[NACC];
#pragma unroll
  for (int k = 0; k < NACC; ++k) a[k] = 0.f;

  stage(0, 0);                          // prologue

#pragma unroll 2
  for (int t = 0; t < TPB; ++t) {
    const int q = t & 1;
    const int i = bi0 + t * TR + w;     // this wave's compute row

    // region codes for tile t -> VGPR (issued BEFORE stage(t+1) so the
    // counted vmcnt below drains them together with stage(t))
    const int4 R0 = *reinterpret_cast<const int4*>(rp + i * NYc + (l << 2));
    const int4 R1 = *reinterpret_cast<const int4*>(rp + i * NYc + 256 + (l << 2));
    asm volatile("" ::: "memory");      // pin issue order: R loads, then stage

    if (t + 1 < TPB) {
      stage(t + 1, q ^ 1);
      // wait for tile t + region loads; leave stage(t+1) in flight.
      if (w < 4) asm volatile("s_waitcnt vmcnt(8)" ::: "memory");
      else       asm volatile("s_waitcnt vmcnt(7)" ::: "memory");
    } else {
      asm volatile("s_waitcnt vmcnt(0)" ::: "memory");
    }
    __builtin_amdgcn_s_barrier();       // all waves: tile t resident
    asm volatile("" ::: "memory");

    const float* Lf = lds + q * BUFE;
#define LF(f, row, col) Lf[(f) * ((TR + 2) * NYc) + (row) * NYc + (col)]

    const bool irow = (i >= 1) & (i <= NXc - 2);

#pragma unroll
    for (int h = 0; h < 2; ++h) {
      const int j0 = h * 256 + (l << 2);

      const float4 Cx = *reinterpret_cast<const float4*>(&LF(0, w + 1, j0));
      const float4 Cy = *reinterpret_cast<const float4*>(&LF(1, w + 1, j0));
      const float4 Cp = *reinterpret_cast<const float4*>(&LF(2, w + 1, j0));
      const float4 Px = *reinterpret_cast<const float4*>(&LF(0, w, j0));
      const float4 Py = *reinterpret_cast<const float4*>(&LF(1, w, j0));
      const float4 Pp = *reinterpret_cast<const float4*>(&LF(2, w, j0));
      const float4 Nx = *reinterpret_cast<const float4*>(&LF(0, w + 2, j0));
      const float4 Ny = *reinterpret_cast<const float4*>(&LF(1, w + 2, j0));
      const float4 Np = *reinterpret_cast<const float4*>(&LF(2, w + 2, j0));
      const int4   R4 = h ? R1 : R0;

      const int jm = (j0 == 0) ? 0 : j0 - 1;             // global edge clamp
      const int jp = (j0 + 4 > NYc - 1) ? NYc - 1 : j0 + 4;
      const float lx = LF(0, w + 1, jm), rx = LF(0, w + 1, jp);
      const float ly = LF(1, w + 1, jm), ry = LF(1, w + 1, jp);
      const float lq = LF(2, w + 1, jm), rq = LF(2, w + 1, jp);

      const float cx[6]  = {lx, Cx.x, Cx.y, Cx.z, Cx.w, rx};
      const float cy_[6] = {ly, Cy.x, Cy.y, Cy.z, Cy.w, ry};
      const float cp_[6] = {lq, Cp.x, Cp.y, Cp.z, Cp.w, rq};
      const float pxA[4] = {Px.x, Px.y, Px.z, Px.w};
      const float pyA[4] = {Py.x, Py.y, Py.z, Py.w};
      const float ppA[4] = {Pp.x, Pp.y, Pp.z, Pp.w};
      const float nxA[4] = {Nx.x, Nx.y, Nx.z, Nx.w};
      const float nyA[4] = {Ny.x, Ny.y, Ny.z, Ny.w};
      const float npA[4] = {Np.x, Np.y, Np.z, Np.w};
      const int   rA[4]  = {R4.x, R4.y, R4.z, R4.w};

#pragma unroll
      for (int e = 0; e < 4; ++e) {
        const int   rg   = rA[e];
        const float c_ux = cx[e + 1], c_uy = cy_[e + 1];
        const float uxm = cx[e],      uxp = cx[e + 2];
        const float uym = cy_[e],     uyp = cy_[e + 2];
        const float pm_ = cp_[e],     pq_ = cp_[e + 2];

        const float ddx_ux = (nxA[e] - pxA[e]) * INV2DX;
        const float ddy_ux = (uxp - uxm) * INV2DY;
        const float ddx_uy = (nyA[e] - pyA[e]) * INV2DX;
        const float ddy_uy = (uyp - uym) * INV2DY;

        const int j = j0 + e;
        const bool jedge = (j == 0) | (j == NYc - 1);
        const bool interior = (rg >= 1) & irow & (!jedge);
        if (interior) {
          const float dv    = ddx_ux + ddy_uy;
          const float d2xux = (nxA[e] - 2.f * c_ux + pxA[e]) * INVDX2;
          const float d2yux = (uxp - 2.f * c_ux + uxm) * INVDY2;
          const float d2xuy = (nyA[e] - 2.f * c_uy + pyA[e]) * INVDX2;
          const float d2yuy = (uyp - 2.f * c_uy + uym) * INVDY2;
          const float ddx_p = (npA[e] - ppA[e]) * INV2DX;
          const float ddy_p = (pq_ - pm_) * INV2DY;
          const float rxv = c_ux * ddx_ux + c_uy * ddy_ux + ddx_p - NU * (d2xux + d2yux);
          const float ryv = c_ux * ddx_uy + c_uy * ddy_uy + ddy_p - NU * (d2xuy + d2yuy);
          a[0] += dv * dv;
          a[1] += rxv * rxv;
          a[2] += ryv * ryv;
          a[3] += 1.f;
        }
        if ((rg == 0) | (rg == 2)) {       // noslip = obstacle | wall
          a[4] += c_ux * c_ux + c_uy * c_uy;
          a[5] += 1.f;
        }
        if (rg == 3) {                      // inlet
          const float d = c_ux - U_INLET;
          a[6] += d * d + c_uy * c_uy;
          a[7] += 1.f;
        }
        if (rg == 4) {                      // outlet
          a[8] += ddx_ux * ddx_ux;
          a[9] += 1.f;
        }
      }
    }
#undef LF

    asm volatile("" ::: "memory");
    __builtin_amdgcn_s_barrier();       // release buffer q before overwrite
  }

  // wave-64 shuffle reduction per accumulator
#pragma unroll
  for (int k = 0; k < NACC; ++k) {
    float v = a[k];
#pragma unroll
    for (int off = 32; off > 0; off >>= 1) v += __shfl_down(v, off, 64);
    a[k] = v;
  }

  // cross-wave reduce via LDS scratch (buffers dead now)
  float* sacc = lds;                    // [8][NACC]
  if (l == 0) {
#pragma unroll
    for (int k = 0; k < NACC; ++k) sacc[w * NACC + k] = a[k];
  }
  __syncthreads();
  if (threadIdx.x < NACC) {
    float s = 0.f;
#pragma unroll
    for (int ww = 0; ww < NTHR / 64; ++ww) s += sacc[ww * NACC + threadIdx.x];
    partial[threadIdx.x * NBLK + blockIdx.x] = s;   // SoA [NACC][NBLK]
  }
}

__global__ __launch_bounds__(256) void pil_finalize(const float* __restrict__ partial,
                                                    float* __restrict__ out) {
  __shared__ double sw[NACC][4];
  const int t = threadIdx.x;
  const int lane = t & 63, wave = t >> 6;
#pragma unroll
  for (int k = 0; k < NACC; ++k) {
    double v = (double)partial[k * NBLK + t];       // NBLK == 256 == blockDim
#pragma unroll
    for (int off = 32; off > 0; off >>= 1) v += __shfl_down(v, off, 64);
    if (lane == 0) sw[k][wave] = v;
  }
  __syncthreads();
  if (t == 0) {
    double acc[NACC];
#pragma unroll
    for (int k = 0; k < NACC; ++k) {
      double s = 0.0;
#pragma unroll
      for (int ww = 0; ww < 4; ++ww) s += sw[k][ww];
      acc[k] = s;
    }
    const double l_cont = acc[0] / fmax(acc[3], 1.0);
    const double l_mom  = (acc[1] + acc[2]) / fmax(acc[3], 1.0);
    const double l_bc   = acc[4] / fmax(acc[5], 1.0)
                        + acc[6] / fmax(acc[7], 1.0)
                        + acc[8] / fmax(acc[9], 1.0);
    const double total  = 1.0 * l_cont + 0.1 * l_mom + 1.0 * l_bc;
    out[0] = (float)l_cont;
    out[1] = (float)l_mom;
    out[2] = (float)l_bc;
    out[3] = (float)total;
  }
}

extern "C" void kernel_launch(void* const* d_in, const int* in_sizes, int n_in,
                              void* d_out, int out_size, void* d_ws, size_t ws_size,
                              hipStream_t stream) {
  const float* y   = (const float*)d_in[0];   // y_hat (16,3,1024,512) f32
  const int*   xin = (const int*)d_in[1];     // x_in  (16,2,1024,512) i32
  float* partial   = (float*)d_ws;            // NACC*NBLK*4 = 10 KB

  const size_t dyn_lds = 2 * (size_t)BUFE * sizeof(float);   // 120 KB
  pil_main<<<NBLK, NTHR, dyn_lds, stream>>>(y, xin, partial);
  pil_finalize<<<1, 256, 0, stream>>>(partial, (float*)d_out);
}

// Round 12
// 53.498 us; speedup vs baseline: 1.6616x; 1.6616x over previous
//
#include <hip/hip_runtime.h>

// PhysicsInformedLoss on (16,3,1024,512) f32 y_hat + (16,2,1024,512) i32 x_in.
// R12: R10's plain stage->sync->compute template (no inline-asm pipeline --
// R11 lesson), tuned: TR=4 rows/block @ 256 thr -> 36KB LDS -> 4 blocks/CU
// (4 independent DMA queues hide each other's vmcnt-drain). Lane owns 8 cols:
// aligned b128 LDS reads + in-register j-neighbors + 2 shuffles per field row
// (kills R11's 4.3M scalar-read bank conflicts). Region codes global->VGPR
// overlapping the DMA. Two-kernel reduce (no device fences).

namespace {
constexpr int NXc  = 1024;
constexpr int NYc  = 512;
constexpr int NXYc = NXc * NYc;
constexpr int NBc  = 16;
constexpr int NTHR = 256;               // 4 waves
constexpr int NACC = 10;
constexpr int TR   = 4;                 // compute rows per block
constexpr int NCH  = NXc / TR;          // 256 chunks per batch
constexpr int NBLK = NBc * NCH;         // 4096 blocks
constexpr int NXCD = 8;
constexpr int QX   = NBLK / NXCD;       // 512 (exact -> bijective swizzle)
// acc: 0 s_div2, 1 s_resx2, 2 s_resy2, 3 n_interior,
//      4 s_noslip, 5 n_noslip, 6 s_inlet, 7 n_inlet, 8 s_outlet, 9 n_outlet
}

__global__ __launch_bounds__(NTHR) void pil_main(const float* __restrict__ y,
                                                 const int* __restrict__ xin,
                                                 float* __restrict__ partial) {
  constexpr double DXd = 0.26 / 1023.0;
  constexpr double DYd = 0.12 / 511.0;
  const float INV2DX = (float)(1.0 / (2.0 * DXd));
  const float INV2DY = (float)(1.0 / (2.0 * DYd));
  const float INVDX2 = (float)(1.0 / (DXd * DXd));
  const float INVDY2 = (float)(1.0 / (DYd * DYd));
  constexpr float NU = 1e-4f;
  constexpr float U_INLET = 0.1f;

  __shared__ float lf[3][TR + 2][NYc];   // 3 fields x 6 rows x 512 = 36 KB

  const int l   = threadIdx.x & 63;
  const int w   = threadIdx.x >> 6;      // wave 0..3
  const int swz = (blockIdx.x % NXCD) * QX + blockIdx.x / NXCD;  // bijective
  const int b   = swz >> 8;              // 256 chunks -> 8 bits
  const int i0  = (swz & (NCH - 1)) * TR;

  const float* __restrict__ ux = y + (size_t)b * 3 * NXYc;
  const float* __restrict__ uy = ux + NXYc;
  const float* __restrict__ pp = ux + 2 * NXYc;
  const int*   __restrict__ rp = xin + (size_t)(2 * b + 1) * NXYc;

  // ---- DMA-stage 36 x 1KB chunks (3 fields x 6 rows x 2 halves) ----
#pragma unroll
  for (int k = 0; k < 9; ++k) {
    const int c  = k * 4 + w;            // 0..35, bijective over waves
    const int f  = c / 12;
    const int cc = c % 12;
    const int rw = cc >> 1;
    const int h  = cc & 1;
    int gi = i0 - 1 + rw;
    gi = gi < 0 ? 0 : (gi > NXc - 1 ? NXc - 1 : gi);   // edge clamp
    const float* base = (f == 0) ? ux : ((f == 1) ? uy : pp);
    const float* g = base + gi * NYc + h * 256 + l * 4;
    float* d = &lf[f][rw][h * 256];
    __builtin_amdgcn_global_load_lds(
        (const __attribute__((address_space(1))) void*)g,
        (__attribute__((address_space(3))) void*)d, 16, 0, 0);
  }

  // region codes for this wave's row -> VGPRs (overlaps the DMA)
  const int i = i0 + w;                   // global row this wave computes
  const int jc = l << 3;                  // 8 cols per lane
  const int4 R0 = *reinterpret_cast<const int4*>(rp + i * NYc + jc);
  const int4 R1 = *reinterpret_cast<const int4*>(rp + i * NYc + jc + 4);

  __syncthreads();   // vmcnt drain + barrier: LDS tile resident

  // ---- compute: wave w -> row i = i0+w, lane owns cols jc..jc+7 ----
  const float4 Cxl = *reinterpret_cast<const float4*>(&lf[0][w + 1][jc]);
  const float4 Cxh = *reinterpret_cast<const float4*>(&lf[0][w + 1][jc + 4]);
  const float4 Cyl = *reinterpret_cast<const float4*>(&lf[1][w + 1][jc]);
  const float4 Cyh = *reinterpret_cast<const float4*>(&lf[1][w + 1][jc + 4]);
  const float4 Cpl = *reinterpret_cast<const float4*>(&lf[2][w + 1][jc]);
  const float4 Cph = *reinterpret_cast<const float4*>(&lf[2][w + 1][jc + 4]);
  const float4 Pxl = *reinterpret_cast<const float4*>(&lf[0][w][jc]);
  const float4 Pxh = *reinterpret_cast<const float4*>(&lf[0][w][jc + 4]);
  const float4 Pyl = *reinterpret_cast<const float4*>(&lf[1][w][jc]);
  const float4 Pyh = *reinterpret_cast<const float4*>(&lf[1][w][jc + 4]);
  const float4 Ppl = *reinterpret_cast<const float4*>(&lf[2][w][jc]);
  const float4 Pph = *reinterpret_cast<const float4*>(&lf[2][w][jc + 4]);
  const float4 Nxl = *reinterpret_cast<const float4*>(&lf[0][w + 2][jc]);
  const float4 Nxh = *reinterpret_cast<const float4*>(&lf[0][w + 2][jc + 4]);
  const float4 Nyl = *reinterpret_cast<const float4*>(&lf[1][w + 2][jc]);
  const float4 Nyh = *reinterpret_cast<const float4*>(&lf[1][w + 2][jc + 4]);
  const float4 Npl = *reinterpret_cast<const float4*>(&lf[2][w + 2][jc]);
  const float4 Nph = *reinterpret_cast<const float4*>(&lf[2][w + 2][jc + 4]);

  float a[NACC];
#pragma unroll
  for (int k = 0; k < NACC; ++k) a[k] = 0.f;

  const float cx[8]  = {Cxl.x, Cxl.y, Cxl.z, Cxl.w, Cxh.x, Cxh.y, Cxh.z, Cxh.w};
  const float cy_[8] = {Cyl.x, Cyl.y, Cyl.z, Cyl.w, Cyh.x, Cyh.y, Cyh.z, Cyh.w};
  const float cp_[8] = {Cpl.x, Cpl.y, Cpl.z, Cpl.w, Cph.x, Cph.y, Cph.z, Cph.w};
  const float pxA[8] = {Pxl.x, Pxl.y, Pxl.z, Pxl.w, Pxh.x, Pxh.y, Pxh.z, Pxh.w};
  const float pyA[8] = {Pyl.x, Pyl.y, Pyl.z, Pyl.w, Pyh.x, Pyh.y, Pyh.z, Pyh.w};
  const float ppA[8] = {Ppl.x, Ppl.y, Ppl.z, Ppl.w, Pph.x, Pph.y, Pph.z, Pph.w};
  const float nxA[8] = {Nxl.x, Nxl.y, Nxl.z, Nxl.w, Nxh.x, Nxh.y, Nxh.z, Nxh.w};
  const float nyA[8] = {Nyl.x, Nyl.y, Nyl.z, Nyl.w, Nyh.x, Nyh.y, Nyh.z, Nyh.w};
  const float npA[8] = {Npl.x, Npl.y, Npl.z, Npl.w, Nph.x, Nph.y, Nph.z, Nph.w};
  const int   rA[8]  = {R0.x, R0.y, R0.z, R0.w, R1.x, R1.y, R1.z, R1.w};

  // j-neighbors across lanes (2 shuffles per field; edge lanes clamp --
  // edge cols are never interior, and outlet term uses ddx only)
  float lxx = __shfl_up(cx[7], 1, 64);    if (l == 0)  lxx = cx[0];
  float rxx = __shfl_down(cx[0], 1, 64);  if (l == 63) rxx = cx[7];
  float lyy = __shfl_up(cy_[7], 1, 64);   if (l == 0)  lyy = cy_[0];
  float ryy = __shfl_down(cy_[0], 1, 64); if (l == 63) ryy = cy_[7];
  float lpp = __shfl_up(cp_[7], 1, 64);   if (l == 0)  lpp = cp_[0];
  float rpp = __shfl_down(cp_[0], 1, 64); if (l == 63) rpp = cp_[7];

  const bool irow = (i >= 1) & (i <= NXc - 2);

#pragma unroll
  for (int e = 0; e < 8; ++e) {
    const int   r    = rA[e];
    const float c_ux = cx[e], c_uy = cy_[e];
    const float uxm = (e == 0) ? lxx : cx[e - 1];
    const float uxp = (e == 7) ? rxx : cx[e + 1];
    const float uym = (e == 0) ? lyy : cy_[e - 1];
    const float uyp = (e == 7) ? ryy : cy_[e + 1];
    const float pm_ = (e == 0) ? lpp : cp_[e - 1];
    const float pq_ = (e == 7) ? rpp : cp_[e + 1];

    const float ddx_ux = (nxA[e] - pxA[e]) * INV2DX;
    const float ddy_ux = (uxp - uxm) * INV2DY;
    const float ddx_uy = (nyA[e] - pyA[e]) * INV2DX;
    const float ddy_uy = (uyp - uym) * INV2DY;

    const bool jedge = ((l == 0) & (e == 0)) | ((l == 63) & (e == 7));
    const bool interior = (r >= 1) & irow & (!jedge);
    if (interior) {
      const float dv    = ddx_ux + ddy_uy;
      const float d2xux = (nxA[e] - 2.f * c_ux + pxA[e]) * INVDX2;
      const float d2yux = (uxp - 2.f * c_ux + uxm) * INVDY2;
      const float d2xuy = (nyA[e] - 2.f * c_uy + pyA[e]) * INVDX2;
      const float d2yuy = (uyp - 2.f * c_uy + uym) * INVDY2;
      const float ddx_p = (npA[e] - ppA[e]) * INV2DX;
      const float ddy_p = (pq_ - pm_) * INV2DY;
      const float rxv = c_ux * ddx_ux + c_uy * ddy_ux + ddx_p - NU * (d2xux + d2yux);
      const float ryv = c_ux * ddx_uy + c_uy * ddy_uy + ddy_p - NU * (d2xuy + d2yuy);
      a[0] += dv * dv;
      a[1] += rxv * rxv;
      a[2] += ryv * ryv;
      a[3] += 1.f;
    }
    if ((r == 0) | (r == 2)) {           // noslip = obstacle | wall
      a[4] += c_ux * c_ux + c_uy * c_uy;
      a[5] += 1.f;
    }
    if (r == 3) {                         // inlet
      const float d = c_ux - U_INLET;
      a[6] += d * d + c_uy * c_uy;
      a[7] += 1.f;
    }
    if (r == 4) {                         // outlet
      a[8] += ddx_ux * ddx_ux;
      a[9] += 1.f;
    }
  }

  // wave-64 shuffle reduction per accumulator
#pragma unroll
  for (int k = 0; k < NACC; ++k) {
    float v = a[k];
#pragma unroll
    for (int off = 32; off > 0; off >>= 1) v += __shfl_down(v, off, 64);
    a[k] = v;
  }

  __shared__ float sacc[NTHR / 64][NACC];
  if (l == 0) {
#pragma unroll
    for (int k = 0; k < NACC; ++k) sacc[w][k] = a[k];
  }
  __syncthreads();
  if (threadIdx.x < NACC) {
    float s = 0.f;
#pragma unroll
    for (int ww = 0; ww < NTHR / 64; ++ww) s += sacc[ww][threadIdx.x];
    partial[threadIdx.x * NBLK + blockIdx.x] = s;   // SoA [NACC][NBLK]
  }
}

__global__ __launch_bounds__(256) void pil_finalize(const float* __restrict__ partial,
                                                    float* __restrict__ out) {
  __shared__ double sw[NACC][4];
  const int t = threadIdx.x;
  const int lane = t & 63, wave = t >> 6;
#pragma unroll
  for (int k = 0; k < NACC; ++k) {
    double v = 0.0;
    const float4* p4 = reinterpret_cast<const float4*>(partial + (size_t)k * NBLK);
    for (int bb = t; bb < NBLK / 4; bb += 256) {
      const float4 q = p4[bb];
      v += (double)q.x + (double)q.y + (double)q.z + (double)q.w;
    }
#pragma unroll
    for (int off = 32; off > 0; off >>= 1) v += __shfl_down(v, off, 64);
    if (lane == 0) sw[k][wave] = v;
  }
  __syncthreads();
  if (t == 0) {
    double acc[NACC];
#pragma unroll
    for (int k = 0; k < NACC; ++k) {
      double s = 0.0;
#pragma unroll
      for (int ww = 0; ww < 4; ++ww) s += sw[k][ww];
      acc[k] = s;
    }
    const double l_cont = acc[0] / fmax(acc[3], 1.0);
    const double l_mom  = (acc[1] + acc[2]) / fmax(acc[3], 1.0);
    const double l_bc   = acc[4] / fmax(acc[5], 1.0)
                        + acc[6] / fmax(acc[7], 1.0)
                        + acc[8] / fmax(acc[9], 1.0);
    const double total  = 1.0 * l_cont + 0.1 * l_mom + 1.0 * l_bc;
    out[0] = (float)l_cont;
    out[1] = (float)l_mom;
    out[2] = (float)l_bc;
    out[3] = (float)total;
  }
}

extern "C" void kernel_launch(void* const* d_in, const int* in_sizes, int n_in,
                              void* d_out, int out_size, void* d_ws, size_t ws_size,
                              hipStream_t stream) {
  const float* y   = (const float*)d_in[0];   // y_hat (16,3,1024,512) f32
  const int*   xin = (const int*)d_in[1];     // x_in  (16,2,1024,512) i32
  float* partial   = (float*)d_ws;            // NACC*NBLK*4 = 160 KB

  pil_main<<<NBLK, NTHR, 0, stream>>>(y, xin, partial);
  pil_finalize<<<1, 256, 0, stream>>>(partial, (float*)d_out);
}

// Round 13
// 45.232 us; speedup vs baseline: 1.9652x; 1.1828x over previous
//
#include <hip/hip_runtime.h>

// PhysicsInformedLoss on (16,3,1024,512) f32 y_hat + (16,2,1024,512) i32 x_in.
// R13: zero-halo DMA staging. Model from R10/R12: main time = staged bytes /
// ~3.9 TB/s. So stage ONLY the 8 owned rows (48KB LDS, 100.7MB total = 1.0x);
// halo rows (i0-1, i0+8) fetched global->VGPR by waves 0/7 only (wave-uniform
// branch); region codes global->VGPR overlapping DMA. Compute = R12's
// verified 8-cols/lane + shfl j-neighbors (no scalar LDS halo reads).
// Two-kernel reduce (R5/R6: no device fences). No forced launch_bounds (R5).

namespace {
constexpr int NXc  = 1024;
constexpr int NYc  = 512;
constexpr int NXYc = NXc * NYc;
constexpr int NBc  = 16;
constexpr int NTHR = 512;               // 8 waves
constexpr int NACC = 10;
constexpr int TR   = 8;                 // rows per block, one per wave
constexpr int NCH  = NXc / TR;          // 128 chunks per batch
constexpr int NBLK = NBc * NCH;         // 2048 blocks
constexpr int NXCD = 8;
constexpr int QX   = NBLK / NXCD;       // 256 (exact -> bijective swizzle)
// acc: 0 s_div2, 1 s_resx2, 2 s_resy2, 3 n_interior,
//      4 s_noslip, 5 n_noslip, 6 s_inlet, 7 n_inlet, 8 s_outlet, 9 n_outlet
}

__global__ __launch_bounds__(NTHR) void pil_main(const float* __restrict__ y,
                                                 const int* __restrict__ xin,
                                                 float* __restrict__ partial) {
  constexpr double DXd = 0.26 / 1023.0;
  constexpr double DYd = 0.12 / 511.0;
  const float INV2DX = (float)(1.0 / (2.0 * DXd));
  const float INV2DY = (float)(1.0 / (2.0 * DYd));
  const float INVDX2 = (float)(1.0 / (DXd * DXd));
  const float INVDY2 = (float)(1.0 / (DYd * DYd));
  constexpr float NU = 1e-4f;
  constexpr float U_INLET = 0.1f;

  __shared__ float lf[3][TR][NYc];       // 3 fields x 8 owned rows = 48 KB

  const int l   = threadIdx.x & 63;
  const int w   = threadIdx.x >> 6;      // wave 0..7
  const int swz = (blockIdx.x % NXCD) * QX + blockIdx.x / NXCD;  // bijective
  const int b   = swz >> 7;              // 128 chunks -> 7 bits
  const int i0  = (swz & (NCH - 1)) * TR;

  const float* __restrict__ ux = y + (size_t)b * 3 * NXYc;
  const float* __restrict__ uy = ux + NXYc;
  const float* __restrict__ pp = ux + 2 * NXYc;
  const int*   __restrict__ rp = xin + (size_t)(2 * b + 1) * NXYc;

  // ---- DMA-stage 48 x 1KB chunks (3 fields x 8 rows x 2 halves), no halo ---
#pragma unroll
  for (int k = 0; k < 6; ++k) {
    const int c  = k * 8 + w;            // 0..47, bijective over waves
    const int f  = c >> 4;               // 0..2
    const int cc = c & 15;
    const int rw = cc >> 1;              // 0..7
    const int h  = cc & 1;
    const float* base = (f == 0) ? ux : ((f == 1) ? uy : pp);
    const float* g = base + (i0 + rw) * NYc + h * 256 + l * 4;
    float* d = &lf[f][rw][h * 256];
    __builtin_amdgcn_global_load_lds(
        (const __attribute__((address_space(1))) void*)g,
        (__attribute__((address_space(3))) void*)d, 16, 0, 0);
  }

  const int i  = i0 + w;                 // this wave's compute row
  const int jc = l << 3;                 // 8 cols per lane

  // region codes -> VGPR (overlaps DMA)
  const int4 R0 = *reinterpret_cast<const int4*>(rp + i * NYc + jc);
  const int4 R1 = *reinterpret_cast<const int4*>(rp + i * NYc + jc + 4);

  // halo rows -> VGPR, boundary waves only (wave-uniform branch)
  float4 Hxl = {}, Hxh = {}, Hyl = {}, Hyh = {}, Hpl = {}, Hph = {};
  if ((w == 0) | (w == 7)) {
    const int hr = (w == 0) ? (i0 > 0 ? i0 - 1 : 0)
                            : (i0 + TR < NXc ? i0 + TR : NXc - 1);
    Hxl = *reinterpret_cast<const float4*>(ux + hr * NYc + jc);
    Hxh = *reinterpret_cast<const float4*>(ux + hr * NYc + jc + 4);
    Hyl = *reinterpret_cast<const float4*>(uy + hr * NYc + jc);
    Hyh = *reinterpret_cast<const float4*>(uy + hr * NYc + jc + 4);
    Hpl = *reinterpret_cast<const float4*>(pp + hr * NYc + jc);
    Hph = *reinterpret_cast<const float4*>(pp + hr * NYc + jc + 4);
  }

  __syncthreads();   // vmcnt drain + barrier: owned rows resident

  // ---- compute: wave w -> row i, lane owns cols jc..jc+7 ----
  const float4 Cxl = *reinterpret_cast<const float4*>(&lf[0][w][jc]);
  const float4 Cxh = *reinterpret_cast<const float4*>(&lf[0][w][jc + 4]);
  const float4 Cyl = *reinterpret_cast<const float4*>(&lf[1][w][jc]);
  const float4 Cyh = *reinterpret_cast<const float4*>(&lf[1][w][jc + 4]);
  const float4 Cpl = *reinterpret_cast<const float4*>(&lf[2][w][jc]);
  const float4 Cph = *reinterpret_cast<const float4*>(&lf[2][w][jc + 4]);

  float4 Pxl, Pxh, Pyl, Pyh, Ppl, Pph;
  if (w > 0) {
    Pxl = *reinterpret_cast<const float4*>(&lf[0][w - 1][jc]);
    Pxh = *reinterpret_cast<const float4*>(&lf[0][w - 1][jc + 4]);
    Pyl = *reinterpret_cast<const float4*>(&lf[1][w - 1][jc]);
    Pyh = *reinterpret_cast<const float4*>(&lf[1][w - 1][jc + 4]);
    Ppl = *reinterpret_cast<const float4*>(&lf[2][w - 1][jc]);
    Pph = *reinterpret_cast<const float4*>(&lf[2][w - 1][jc + 4]);
  } else {
    Pxl = Hxl; Pxh = Hxh; Pyl = Hyl; Pyh = Hyh; Ppl = Hpl; Pph = Hph;
  }
  float4 Nxl, Nxh, Nyl, Nyh, Npl, Nph;
  if (w < TR - 1) {
    Nxl = *reinterpret_cast<const float4*>(&lf[0][w + 1][jc]);
    Nxh = *reinterpret_cast<const float4*>(&lf[0][w + 1][jc + 4]);
    Nyl = *reinterpret_cast<const float4*>(&lf[1][w + 1][jc]);
    Nyh = *reinterpret_cast<const float4*>(&lf[1][w + 1][jc + 4]);
    Npl = *reinterpret_cast<const float4*>(&lf[2][w + 1][jc]);
    Nph = *reinterpret_cast<const float4*>(&lf[2][w + 1][jc + 4]);
  } else {
    Nxl = Hxl; Nxh = Hxh; Nyl = Hyl; Nyh = Hyh; Npl = Hpl; Nph = Hph;
  }

  float a[NACC];
#pragma unroll
  for (int k = 0; k < NACC; ++k) a[k] = 0.f;

  const float cx[8]  = {Cxl.x, Cxl.y, Cxl.z, Cxl.w, Cxh.x, Cxh.y, Cxh.z, Cxh.w};
  const float cy_[8] = {Cyl.x, Cyl.y, Cyl.z, Cyl.w, Cyh.x, Cyh.y, Cyh.z, Cyh.w};
  const float cp_[8] = {Cpl.x, Cpl.y, Cpl.z, Cpl.w, Cph.x, Cph.y, Cph.z, Cph.w};
  const float pxA[8] = {Pxl.x, Pxl.y, Pxl.z, Pxl.w, Pxh.x, Pxh.y, Pxh.z, Pxh.w};
  const float pyA[8] = {Pyl.x, Pyl.y, Pyl.z, Pyl.w, Pyh.x, Pyh.y, Pyh.z, Pyh.w};
  const float ppA[8] = {Ppl.x, Ppl.y, Ppl.z, Ppl.w, Pph.x, Pph.y, Pph.z, Pph.w};
  const float nxA[8] = {Nxl.x, Nxl.y, Nxl.z, Nxl.w, Nxh.x, Nxh.y, Nxh.z, Nxh.w};
  const float nyA[8] = {Nyl.x, Nyl.y, Nyl.z, Nyl.w, Nyh.x, Nyh.y, Nyh.z, Nyh.w};
  const float npA[8] = {Npl.x, Npl.y, Npl.z, Npl.w, Nph.x, Nph.y, Nph.z, Nph.w};
  const int   rA[8]  = {R0.x, R0.y, R0.z, R0.w, R1.x, R1.y, R1.z, R1.w};

  // j-neighbors across lanes (2 shuffles per field; edge lanes clamp --
  // edge cols are never interior, and outlet term uses ddx only)
  float lxx = __shfl_up(cx[7], 1, 64);    if (l == 0)  lxx = cx[0];
  float rxx = __shfl_down(cx[0], 1, 64);  if (l == 63) rxx = cx[7];
  float lyy = __shfl_up(cy_[7], 1, 64);   if (l == 0)  lyy = cy_[0];
  float ryy = __shfl_down(cy_[0], 1, 64); if (l == 63) ryy = cy_[7];
  float lpp = __shfl_up(cp_[7], 1, 64);   if (l == 0)  lpp = cp_[0];
  float rpp = __shfl_down(cp_[0], 1, 64); if (l == 63) rpp = cp_[7];

  const bool irow = (i >= 1) & (i <= NXc - 2);

#pragma unroll
  for (int e = 0; e < 8; ++e) {
    const int   r    = rA[e];
    const float c_ux = cx[e], c_uy = cy_[e];
    const float uxm = (e == 0) ? lxx : cx[e - 1];
    const float uxp = (e == 7) ? rxx : cx[e + 1];
    const float uym = (e == 0) ? lyy : cy_[e - 1];
    const float uyp = (e == 7) ? ryy : cy_[e + 1];
    const float pm_ = (e == 0) ? lpp : cp_[e - 1];
    const float pq_ = (e == 7) ? rpp : cp_[e + 1];

    const float ddx_ux = (nxA[e] - pxA[e]) * INV2DX;
    const float ddy_ux = (uxp - uxm) * INV2DY;
    const float ddx_uy = (nyA[e] - pyA[e]) * INV2DX;
    const float ddy_uy = (uyp - uym) * INV2DY;

    const bool jedge = ((l == 0) & (e == 0)) | ((l == 63) & (e == 7));
    const bool interior = (r >= 1) & irow & (!jedge);
    if (interior) {
      const float dv    = ddx_ux + ddy_uy;
      const float d2xux = (nxA[e] - 2.f * c_ux + pxA[e]) * INVDX2;
      const float d2yux = (uxp - 2.f * c_ux + uxm) * INVDY2;
      const float d2xuy = (nyA[e] - 2.f * c_uy + pyA[e]) * INVDX2;
      const float d2yuy = (uyp - 2.f * c_uy + uym) * INVDY2;
      const float ddx_p = (npA[e] - ppA[e]) * INV2DX;
      const float ddy_p = (pq_ - pm_) * INV2DY;
      const float rxv = c_ux * ddx_ux + c_uy * ddy_ux + ddx_p - NU * (d2xux + d2yux);
      const float ryv = c_ux * ddx_uy + c_uy * ddy_uy + ddy_p - NU * (d2xuy + d2yuy);
      a[0] += dv * dv;
      a[1] += rxv * rxv;
      a[2] += ryv * ryv;
      a[3] += 1.f;
    }
    if ((r == 0) | (r == 2)) {           // noslip = obstacle | wall
      a[4] += c_ux * c_ux + c_uy * c_uy;
      a[5] += 1.f;
    }
    if (r == 3) {                         // inlet
      const float d = c_ux - U_INLET;
      a[6] += d * d + c_uy * c_uy;
      a[7] += 1.f;
    }
    if (r == 4) {                         // outlet
      a[8] += ddx_ux * ddx_ux;
      a[9] += 1.f;
    }
  }

  // wave-64 shuffle reduction per accumulator
#pragma unroll
  for (int k = 0; k < NACC; ++k) {
    float v = a[k];
#pragma unroll
    for (int off = 32; off > 0; off >>= 1) v += __shfl_down(v, off, 64);
    a[k] = v;
  }

  __shared__ float sacc[NTHR / 64][NACC];
  if (l == 0) {
#pragma unroll
    for (int k = 0; k < NACC; ++k) sacc[w][k] = a[k];
  }
  __syncthreads();
  if (threadIdx.x < NACC) {
    float s = 0.f;
#pragma unroll
    for (int ww = 0; ww < NTHR / 64; ++ww) s += sacc[ww][threadIdx.x];
    partial[threadIdx.x * NBLK + blockIdx.x] = s;   // SoA [NACC][NBLK]
  }
}

__global__ __launch_bounds__(256) void pil_finalize(const float* __restrict__ partial,
                                                    float* __restrict__ out) {
  __shared__ double sw[NACC][4];
  const int t = threadIdx.x;
  const int lane = t & 63, wave = t >> 6;
#pragma unroll
  for (int k = 0; k < NACC; ++k) {
    double v = 0.0;
    const float4* p4 = reinterpret_cast<const float4*>(partial + (size_t)k * NBLK);
    for (int bb = t; bb < NBLK / 4; bb += 256) {
      const float4 q = p4[bb];
      v += (double)q.x + (double)q.y + (double)q.z + (double)q.w;
    }
#pragma unroll
    for (int off = 32; off > 0; off >>= 1) v += __shfl_down(v, off, 64);
    if (lane == 0) sw[k][wave] = v;
  }
  __syncthreads();
  if (t == 0) {
    double acc[NACC];
#pragma unroll
    for (int k = 0; k < NACC; ++k) {
      double s = 0.0;
#pragma unroll
      for (int ww = 0; ww < 4; ++ww) s += sw[k][ww];
      acc[k] = s;
    }
    const double l_cont = acc[0] / fmax(acc[3], 1.0);
    const double l_mom  = (acc[1] + acc[2]) / fmax(acc[3], 1.0);
    const double l_bc   = acc[4] / fmax(acc[5], 1.0)
                        + acc[6] / fmax(acc[7], 1.0)
                        + acc[8] / fmax(acc[9], 1.0);
    const double total  = 1.0 * l_cont + 0.1 * l_mom + 1.0 * l_bc;
    out[0] = (float)l_cont;
    out[1] = (float)l_mom;
    out[2] = (float)l_bc;
    out[3] = (float)total;
  }
}

extern "C" void kernel_launch(void* const* d_in, const int* in_sizes, int n_in,
                              void* d_out, int out_size, void* d_ws, size_t ws_size,
                              hipStream_t stream) {
  const float* y   = (const float*)d_in[0];   // y_hat (16,3,1024,512) f32
  const int*   xin = (const int*)d_in[1];     // x_in  (16,2,1024,512) i32
  float* partial   = (float*)d_ws;            // NACC*NBLK*4 = 80 KB

  pil_main<<<NBLK, NTHR, 0, stream>>>(y, xin, partial);
  pil_finalize<<<1, 256, 0, stream>>>(partial, (float*)d_out);
}

// Round 14
// 44.512 us; speedup vs baseline: 1.9970x; 1.0162x over previous
//
#include <hip/hip_runtime.h>

// PhysicsInformedLoss on (16,3,1024,512) f32 y_hat + (16,2,1024,512) i32 x_in.
// R14: R13's zero-halo DMA template with 6 queues/CU. TR=4 @ 256 thr ->
// 24 KB LDS -> 6 blocks/CU; staged bytes stay 1.0x (100.7 MB); halo rows
// (2 per block) are wave-uniform VGPR loads by waves 0/3 (same-XCD L2 warm
// via bijective swizzle). Region codes global->VGPR overlap the DMA.
// Two-kernel reduce (R5/R6: no device fences). No forced launch_bounds (R5).

namespace {
constexpr int NXc  = 1024;
constexpr int NYc  = 512;
constexpr int NXYc = NXc * NYc;
constexpr int NBc  = 16;
constexpr int NTHR = 256;               // 4 waves
constexpr int NACC = 10;
constexpr int TR   = 4;                 // rows per block, one per wave
constexpr int NCH  = NXc / TR;          // 256 chunks per batch
constexpr int NBLK = NBc * NCH;         // 4096 blocks
constexpr int NXCD = 8;
constexpr int QX   = NBLK / NXCD;       // 512 (exact -> bijective swizzle)
// acc: 0 s_div2, 1 s_resx2, 2 s_resy2, 3 n_interior,
//      4 s_noslip, 5 n_noslip, 6 s_inlet, 7 n_inlet, 8 s_outlet, 9 n_outlet
}

__global__ __launch_bounds__(NTHR) void pil_main(const float* __restrict__ y,
                                                 const int* __restrict__ xin,
                                                 float* __restrict__ partial) {
  constexpr double DXd = 0.26 / 1023.0;
  constexpr double DYd = 0.12 / 511.0;
  const float INV2DX = (float)(1.0 / (2.0 * DXd));
  const float INV2DY = (float)(1.0 / (2.0 * DYd));
  const float INVDX2 = (float)(1.0 / (DXd * DXd));
  const float INVDY2 = (float)(1.0 / (DYd * DYd));
  constexpr float NU = 1e-4f;
  constexpr float U_INLET = 0.1f;

  __shared__ float lf[3][TR][NYc];       // 3 fields x 4 owned rows = 24 KB

  const int l   = threadIdx.x & 63;
  const int w   = threadIdx.x >> 6;      // wave 0..3
  const int swz = (blockIdx.x % NXCD) * QX + blockIdx.x / NXCD;  // bijective
  const int b   = swz >> 8;              // 256 chunks -> 8 bits
  const int i0  = (swz & (NCH - 1)) * TR;

  const float* __restrict__ ux = y + (size_t)b * 3 * NXYc;
  const float* __restrict__ uy = ux + NXYc;
  const float* __restrict__ pp = ux + 2 * NXYc;
  const int*   __restrict__ rp = xin + (size_t)(2 * b + 1) * NXYc;

  // ---- DMA-stage 24 x 1KB chunks (3 fields x 4 rows x 2 halves), no halo ---
#pragma unroll
  for (int k = 0; k < 6; ++k) {
    const int c  = k * 4 + w;            // 0..23, bijective over waves
    const int f  = c >> 3;               // 0..2
    const int cc = c & 7;
    const int rw = cc >> 1;              // 0..3
    const int h  = cc & 1;
    const float* base = (f == 0) ? ux : ((f == 1) ? uy : pp);
    const float* g = base + (i0 + rw) * NYc + h * 256 + l * 4;
    float* d = &lf[f][rw][h * 256];
    __builtin_amdgcn_global_load_lds(
        (const __attribute__((address_space(1))) void*)g,
        (__attribute__((address_space(3))) void*)d, 16, 0, 0);
  }

  const int i  = i0 + w;                 // this wave's compute row
  const int jc = l << 3;                 // 8 cols per lane

  // region codes -> VGPR (overlaps DMA)
  const int4 R0 = *reinterpret_cast<const int4*>(rp + i * NYc + jc);
  const int4 R1 = *reinterpret_cast<const int4*>(rp + i * NYc + jc + 4);

  // halo rows -> VGPR, boundary waves only (wave-uniform branch)
  float4 Hxl = {}, Hxh = {}, Hyl = {}, Hyh = {}, Hpl = {}, Hph = {};
  if ((w == 0) | (w == TR - 1)) {
    const int hr = (w == 0) ? (i0 > 0 ? i0 - 1 : 0)
                            : (i0 + TR < NXc ? i0 + TR : NXc - 1);
    Hxl = *reinterpret_cast<const float4*>(ux + hr * NYc + jc);
    Hxh = *reinterpret_cast<const float4*>(ux + hr * NYc + jc + 4);
    Hyl = *reinterpret_cast<const float4*>(uy + hr * NYc + jc);
    Hyh = *reinterpret_cast<const float4*>(uy + hr * NYc + jc + 4);
    Hpl = *reinterpret_cast<const float4*>(pp + hr * NYc + jc);
    Hph = *reinterpret_cast<const float4*>(pp + hr * NYc + jc + 4);
  }

  __syncthreads();   // vmcnt drain + barrier: owned rows resident

  // ---- compute: wave w -> row i, lane owns cols jc..jc+7 ----
  const float4 Cxl = *reinterpret_cast<const float4*>(&lf[0][w][jc]);
  const float4 Cxh = *reinterpret_cast<const float4*>(&lf[0][w][jc + 4]);
  const float4 Cyl = *reinterpret_cast<const float4*>(&lf[1][w][jc]);
  const float4 Cyh = *reinterpret_cast<const float4*>(&lf[1][w][jc + 4]);
  const float4 Cpl = *reinterpret_cast<const float4*>(&lf[2][w][jc]);
  const float4 Cph = *reinterpret_cast<const float4*>(&lf[2][w][jc + 4]);

  float4 Pxl, Pxh, Pyl, Pyh, Ppl, Pph;
  if (w > 0) {
    Pxl = *reinterpret_cast<const float4*>(&lf[0][w - 1][jc]);
    Pxh = *reinterpret_cast<const float4*>(&lf[0][w - 1][jc + 4]);
    Pyl = *reinterpret_cast<const float4*>(&lf[1][w - 1][jc]);
    Pyh = *reinterpret_cast<const float4*>(&lf[1][w - 1][jc + 4]);
    Ppl = *reinterpret_cast<const float4*>(&lf[2][w - 1][jc]);
    Pph = *reinterpret_cast<const float4*>(&lf[2][w - 1][jc + 4]);
  } else {
    Pxl = Hxl; Pxh = Hxh; Pyl = Hyl; Pyh = Hyh; Ppl = Hpl; Pph = Hph;
  }
  float4 Nxl, Nxh, Nyl, Nyh, Npl, Nph;
  if (w < TR - 1) {
    Nxl = *reinterpret_cast<const float4*>(&lf[0][w + 1][jc]);
    Nxh = *reinterpret_cast<const float4*>(&lf[0][w + 1][jc + 4]);
    Nyl = *reinterpret_cast<const float4*>(&lf[1][w + 1][jc]);
    Nyh = *reinterpret_cast<const float4*>(&lf[1][w + 1][jc + 4]);
    Npl = *reinterpret_cast<const float4*>(&lf[2][w + 1][jc]);
    Nph = *reinterpret_cast<const float4*>(&lf[2][w + 1][jc + 4]);
  } else {
    Nxl = Hxl; Nxh = Hxh; Nyl = Hyl; Nyh = Hyh; Npl = Hpl; Nph = Hph;
  }

  float a[NACC];
#pragma unroll
  for (int k = 0; k < NACC; ++k) a[k] = 0.f;

  const float cx[8]  = {Cxl.x, Cxl.y, Cxl.z, Cxl.w, Cxh.x, Cxh.y, Cxh.z, Cxh.w};
  const float cy_[8] = {Cyl.x, Cyl.y, Cyl.z, Cyl.w, Cyh.x, Cyh.y, Cyh.z, Cyh.w};
  const float cp_[8] = {Cpl.x, Cpl.y, Cpl.z, Cpl.w, Cph.x, Cph.y, Cph.z, Cph.w};
  const float pxA[8] = {Pxl.x, Pxl.y, Pxl.z, Pxl.w, Pxh.x, Pxh.y, Pxh.z, Pxh.w};
  const float pyA[8] = {Pyl.x, Pyl.y, Pyl.z, Pyl.w, Pyh.x, Pyh.y, Pyh.z, Pyh.w};
  const float ppA[8] = {Ppl.x, Ppl.y, Ppl.z, Ppl.w, Pph.x, Pph.y, Pph.z, Pph.w};
  const float nxA[8] = {Nxl.x, Nxl.y, Nxl.z, Nxl.w, Nxh.x, Nxh.y, Nxh.z, Nxh.w};
  const float nyA[8] = {Nyl.x, Nyl.y, Nyl.z, Nyl.w, Nyh.x, Nyh.y, Nyh.z, Nyh.w};
  const float npA[8] = {Npl.x, Npl.y, Npl.z, Npl.w, Nph.x, Nph.y, Nph.z, Nph.w};
  const int   rA[8]  = {R0.x, R0.y, R0.z, R0.w, R1.x, R1.y, R1.z, R1.w};

  // j-neighbors across lanes (2 shuffles per field; edge lanes clamp --
  // edge cols are never interior, and outlet term uses ddx only)
  float lxx = __shfl_up(cx[7], 1, 64);    if (l == 0)  lxx = cx[0];
  float rxx = __shfl_down(cx[0], 1, 64);  if (l == 63) rxx = cx[7];
  float lyy = __shfl_up(cy_[7], 1, 64);   if (l == 0)  lyy = cy_[0];
  float ryy = __shfl_down(cy_[0], 1, 64); if (l == 63) ryy = cy_[7];
  float lpp = __shfl_up(cp_[7], 1, 64);   if (l == 0)  lpp = cp_[0];
  float rpp = __shfl_down(cp_[0], 1, 64); if (l == 63) rpp = cp_[7];

  const bool irow = (i >= 1) & (i <= NXc - 2);

#pragma unroll
  for (int e = 0; e < 8; ++e) {
    const int   r    = rA[e];
    const float c_ux = cx[e], c_uy = cy_[e];
    const float uxm = (e == 0) ? lxx : cx[e - 1];
    const float uxp = (e == 7) ? rxx : cx[e + 1];
    const float uym = (e == 0) ? lyy : cy_[e - 1];
    const float uyp = (e == 7) ? ryy : cy_[e + 1];
    const float pm_ = (e == 0) ? lpp : cp_[e - 1];
    const float pq_ = (e == 7) ? rpp : cp_[e + 1];

    const float ddx_ux = (nxA[e] - pxA[e]) * INV2DX;
    const float ddy_ux = (uxp - uxm) * INV2DY;
    const float ddx_uy = (nyA[e] - pyA[e]) * INV2DX;
    const float ddy_uy = (uyp - uym) * INV2DY;

    const bool jedge = ((l == 0) & (e == 0)) | ((l == 63) & (e == 7));
    const bool interior = (r >= 1) & irow & (!jedge);
    if (interior) {
      const float dv    = ddx_ux + ddy_uy;
      const float d2xux = (nxA[e] - 2.f * c_ux + pxA[e]) * INVDX2;
      const float d2yux = (uxp - 2.f * c_ux + uxm) * INVDY2;
      const float d2xuy = (nyA[e] - 2.f * c_uy + pyA[e]) * INVDX2;
      const float d2yuy = (uyp - 2.f * c_uy + uym) * INVDY2;
      const float ddx_p = (npA[e] - ppA[e]) * INV2DX;
      const float ddy_p = (pq_ - pm_) * INV2DY;
      const float rxv = c_ux * ddx_ux + c_uy * ddy_ux + ddx_p - NU * (d2xux + d2yux);
      const float ryv = c_ux * ddx_uy + c_uy * ddy_uy + ddy_p - NU * (d2xuy + d2yuy);
      a[0] += dv * dv;
      a[1] += rxv * rxv;
      a[2] += ryv * ryv;
      a[3] += 1.f;
    }
    if ((r == 0) | (r == 2)) {           // noslip = obstacle | wall
      a[4] += c_ux * c_ux + c_uy * c_uy;
      a[5] += 1.f;
    }
    if (r == 3) {                         // inlet
      const float d = c_ux - U_INLET;
      a[6] += d * d + c_uy * c_uy;
      a[7] += 1.f;
    }
    if (r == 4) {                         // outlet
      a[8] += ddx_ux * ddx_ux;
      a[9] += 1.f;
    }
  }

  // wave-64 shuffle reduction per accumulator
#pragma unroll
  for (int k = 0; k < NACC; ++k) {
    float v = a[k];
#pragma unroll
    for (int off = 32; off > 0; off >>= 1) v += __shfl_down(v, off, 64);
    a[k] = v;
  }

  __shared__ float sacc[NTHR / 64][NACC];
  if (l == 0) {
#pragma unroll
    for (int k = 0; k < NACC; ++k) sacc[w][k] = a[k];
  }
  __syncthreads();
  if (threadIdx.x < NACC) {
    float s = 0.f;
#pragma unroll
    for (int ww = 0; ww < NTHR / 64; ++ww) s += sacc[ww][threadIdx.x];
    partial[threadIdx.x * NBLK + blockIdx.x] = s;   // SoA [NACC][NBLK]
  }
}

__global__ __launch_bounds__(256) void pil_finalize(const float* __restrict__ partial,
                                                    float* __restrict__ out) {
  __shared__ double sw[NACC][4];
  const int t = threadIdx.x;
  const int lane = t & 63, wave = t >> 6;
#pragma unroll
  for (int k = 0; k < NACC; ++k) {
    double v = 0.0;
    const float4* p4 = reinterpret_cast<const float4*>(partial + (size_t)k * NBLK);
    for (int bb = t; bb < NBLK / 4; bb += 256) {
      const float4 q = p4[bb];
      v += (double)q.x + (double)q.y + (double)q.z + (double)q.w;
    }
#pragma unroll
    for (int off = 32; off > 0; off >>= 1) v += __shfl_down(v, off, 64);
    if (lane == 0) sw[k][wave] = v;
  }
  __syncthreads();
  if (t == 0) {
    double acc[NACC];
#pragma unroll
    for (int k = 0; k < NACC; ++k) {
      double s = 0.0;
#pragma unroll
      for (int ww = 0; ww < 4; ++ww) s += sw[k][ww];
      acc[k] = s;
    }
    const double l_cont = acc[0] / fmax(acc[3], 1.0);
    const double l_mom  = (acc[1] + acc[2]) / fmax(acc[3], 1.0);
    const double l_bc   = acc[4] / fmax(acc[5], 1.0)
                        + acc[6] / fmax(acc[7], 1.0)
                        + acc[8] / fmax(acc[9], 1.0);
    const double total  = 1.0 * l_cont + 0.1 * l_mom + 1.0 * l_bc;
    out[0] = (float)l_cont;
    out[1] = (float)l_mom;
    out[2] = (float)l_bc;
    out[3] = (float)total;
  }
}

extern "C" void kernel_launch(void* const* d_in, const int* in_sizes, int n_in,
                              void* d_out, int out_size, void* d_ws, size_t ws_size,
                              hipStream_t stream) {
  const float* y   = (const float*)d_in[0];   // y_hat (16,3,1024,512) f32
  const int*   xin = (const int*)d_in[1];     // x_in  (16,2,1024,512) i32
  float* partial   = (float*)d_ws;            // NACC*NBLK*4 = 160 KB

  pil_main<<<NBLK, NTHR, 0, stream>>>(y, xin, partial);
  pil_finalize<<<1, 256, 0, stream>>>(partial, (float*)d_out);
}